// Round 2
// baseline (323.226 us; speedup 1.0000x reference)
//
#include <hip/hip_runtime.h>

#define N_NODES 50000
#define N_EDGES 800000
#define IN_DIM 128
#define OUT_DIM 64
#define NEG_SLOPE 0.01f

// K0: zero accumulators + denom; compute c = W_feat . Wa_feat
__global__ void k_init(float* __restrict__ acc, float* __restrict__ denom, float* __restrict__ c_ws,
                       const float* __restrict__ W_attn,
                       const float* __restrict__ W_feat) {
    int i = blockIdx.x * blockDim.x + threadIdx.x;
    int stride = gridDim.x * blockDim.x;
    float4* acc4 = (float4*)acc;
    for (int j = i; j < N_NODES * OUT_DIM / 4; j += stride) acc4[j] = make_float4(0.f, 0.f, 0.f, 0.f);
    float4* den4 = (float4*)denom;
    for (int j = i; j < N_NODES / 4; j += stride) den4[j] = make_float4(0.f, 0.f, 0.f, 0.f);
    if (blockIdx.x == 0 && threadIdx.x < 64) {
        int lane = threadIdx.x;
        float p = W_feat[lane] * W_attn[128 + lane];
        #pragma unroll
        for (int off = 32; off; off >>= 1) p += __shfl_xor(p, off, 64);
        if (lane == 0) c_ws[0] = p;
    }
}

// K1: z = h @ W_fc (f32), a_src = z . Wa_src, a_dst = z . Wa_dst
// One wave per node; lane d owns output dim d; W_fc staged in LDS.
__launch_bounds__(256)
__global__ void k_fc(const float* __restrict__ h,
                     const float* __restrict__ W_fc,
                     const float* __restrict__ W_attn,
                     float* __restrict__ z, float* __restrict__ a_src, float* __restrict__ a_dst) {
    __shared__ float Wlds[IN_DIM * OUT_DIM];  // 32 KB
    const float4* Wg = (const float4*)W_fc;
    float4* Wl = (float4*)Wlds;
    for (int i = threadIdx.x; i < IN_DIM * OUT_DIM / 4; i += 256) Wl[i] = Wg[i];
    __syncthreads();

    const int lane = threadIdx.x & 63;
    const int wid  = threadIdx.x >> 6;
    const float was = W_attn[lane];
    const float wad = W_attn[64 + lane];
    const int wavesTotal = gridDim.x * 4;

    for (int n = blockIdx.x * 4 + wid; n < N_NODES; n += wavesTotal) {
        // lane l holds h[n][2l], h[n][2l+1]
        float2 hp = ((const float2*)h)[n * (IN_DIM / 2) + lane];
        float zd = 0.f;
        #pragma unroll
        for (int kk = 0; kk < 64; ++kk) {
            float h0 = __shfl(hp.x, kk, 64);
            float h1 = __shfl(hp.y, kk, 64);
            zd += h0 * Wlds[(2 * kk) * OUT_DIM + lane];
            zd += h1 * Wlds[(2 * kk + 1) * OUT_DIM + lane];
        }
        z[n * OUT_DIM + lane] = zd;
        float ps = zd * was, pd = zd * wad;
        #pragma unroll
        for (int off = 32; off; off >>= 1) {
            ps += __shfl_xor(ps, off, 64);
            pd += __shfl_xor(pd, off, 64);
        }
        if (lane == 0) { a_src[n] = ps; a_dst[n] = pd; }
    }
}

// K2: one wave per edge. e = a_src[s] + a_dst[d] + c*embed; leaky; ex = exp(e)
// (segment-max skipped: alpha is shift-invariant; e is O(5) so f32 exp is safe).
// Scatter ex and ex*z[s] via f32 atomics.
__launch_bounds__(256)
__global__ void k_edge(const int* __restrict__ src, const int* __restrict__ dst,
                       const float* __restrict__ embed,
                       const float* __restrict__ a_src, const float* __restrict__ a_dst,
                       const float* __restrict__ z, const float* __restrict__ c_ws,
                       float* __restrict__ acc, float* __restrict__ denom) {
    int w = (int)((blockIdx.x * 256u + threadIdx.x) >> 6);
    if (w >= N_EDGES) return;
    int lane = threadIdx.x & 63;
    int s = src[w], d = dst[w];
    float e = a_src[s] + a_dst[d] + c_ws[0] * embed[w];
    e = (e >= 0.f) ? e : NEG_SLOPE * e;
    float ex = __expf(e);
    if (lane == 0) atomicAdd(denom + d, ex);
    atomicAdd(acc + d * OUT_DIM + lane, ex * z[s * OUT_DIM + lane]);
}

// K3: out = acc / denom (f32), guard empty segments
__global__ void k_final(const float* __restrict__ acc, const float* __restrict__ denom,
                        float* __restrict__ out) {
    int i = blockIdx.x * blockDim.x + threadIdx.x;
    if (i >= N_NODES * OUT_DIM) return;
    float den = denom[i >> 6];
    float v = (den > 0.f) ? acc[i] / den : 0.f;
    out[i] = v;
}

extern "C" void kernel_launch(void* const* d_in, const int* in_sizes, int n_in,
                              void* d_out, int out_size, void* d_ws, size_t ws_size,
                              hipStream_t stream) {
    const float* h      = (const float*)d_in[0];
    const float* embed  = (const float*)d_in[1];
    const int*   src    = (const int*)d_in[2];
    const int*   dst    = (const int*)d_in[3];
    const float* W_fc   = (const float*)d_in[4];
    const float* W_attn = (const float*)d_in[5];
    const float* W_feat = (const float*)d_in[6];

    float* ws    = (float*)d_ws;
    float* z     = ws;                        // N*64
    float* acc   = z + N_NODES * OUT_DIM;     // N*64
    float* a_src = acc + N_NODES * OUT_DIM;   // N
    float* a_dst = a_src + N_NODES;           // N
    float* denom = a_dst + N_NODES;           // N
    float* c_ws  = denom + N_NODES;           // 1

    float* out = (float*)d_out;

    k_init<<<1024, 256, 0, stream>>>(acc, denom, c_ws, W_attn, W_feat);
    k_fc<<<1024, 256, 0, stream>>>(h, W_fc, W_attn, z, a_src, a_dst);
    k_edge<<<(N_EDGES * 64) / 256, 256, 0, stream>>>(src, dst, embed, a_src, a_dst, z, c_ws, acc, denom);
    k_final<<<(N_NODES * OUT_DIM + 255) / 256, 256, 0, stream>>>(acc, denom, out);
}